// Round 6
// baseline (293.382 us; speedup 1.0000x reference)
//
#include <hip/hip_runtime.h>
#include <math.h>

// CTC forward (keras ctc_batch_cost), B=1024 T=256 C=128 L=64, S=129.
// R11 = R5 (best, 192.17us) + a ~100us s_sleep tail for INSTRUMENTATION.
// Purpose: the ctc kernel has never appeared in the top-5 rocprof rows
// (the ~77us poison fills crowd it out), so its true duration, FETCH_SIZE
// and occupancy have never been observed -- every R6-R10 theory was built
// on the inference kernel ~= total - 2 fills ~= 37us, which may be wrong
// if tiny memset/restore dispatches + launch gaps eat 10-15us.
// The sleep tail (30 x s_sleep(127) ~= 8128cy each ~= 102us) lifts the
// kernel above the fill cutoff. True kernel time = row_dur - (new_total -
// 192.17). Pre-committed decision: <=26us -> revert to R5, declare
// roofline; >=33us -> optimize with real counters in hand.
//  - Pipeline identical to R5: 7-deep LDS ring, global_load_lds 16B,
//    manual vmcnt (steady wait 20), q-values one chunk ahead, probability-
//    domain semiring with x128 bias + renorm every 8 steps.

#define Bn 1024
#define Tn 256
#define Cn 128
#define Ln 64
#define BLANK 127
#define U 8
#define NC (Tn / U)       // 32 chunks
#define RING 8
#define DEPTH 7           // chunks in flight: 7*4 = 28 loads <= 63
#define EPS128 (1e-7f * 128.0f)
#define LN2 0.69314718055994530942f

// s_waitcnt imm: vmcnt bits [3:0]+[15:14]; expcnt[6:4]=7, lgkmcnt[11:8]=0xF don't-care
#define WAIT_VM(n) __builtin_amdgcn_s_waitcnt((((n) & 0xF) | (((n) >> 4) << 14)) | 0x0F70)
#define SCHED_FENCE() __builtin_amdgcn_sched_barrier(0)

template <int CTRL>
__device__ __forceinline__ float dpp_movf(float x) {
    return __int_as_float(__builtin_amdgcn_update_dpp(
        0, __float_as_int(x), CTRL, 0xF, 0xF, true));
}
__device__ __forceinline__ int dpp_shr1_i(int x) {
    return __builtin_amdgcn_update_dpp(0, x, 0x138, 0xF, 0xF, true);
}
__device__ __forceinline__ void dma16(const float* g, float* l) {
    __builtin_amdgcn_global_load_lds(
        (const __attribute__((address_space(1))) void*)g,
        (__attribute__((address_space(3))) void*)l, 16, 0, 0);
}

__global__ __launch_bounds__(64)
void ctc_ring_kernel(const int* __restrict__ y_true,
                     const float* __restrict__ y_pred,
                     float* __restrict__ out) {
    __shared__ __align__(16) float ring[RING][U * Cn];   // 32 KB
    const int b = blockIdx.x;
    const int i = threadIdx.x;

    const int li = y_true[b * Ln + i];
    const int ll = dpp_shr1_i(li);                 // lab[i-1] (lane0 -> 0)
    const float skf = (li != ll) ? 1.0f : 0.0f;

    const float* gb = y_pred + (size_t)b * (Tn * Cn);

    auto issue_chunk = [&](int c) {
        const float* g = gb + c * (U * Cn);
        float* l = ring[c & (RING - 1)];
#pragma unroll
        for (int k = 0; k < 4; ++k)                // 4 x (64 lanes x 16B) = 4 KB
            dma16(g + k * 256 + i * 4, l + k * 256);
    };

    float qlA[U], qbA[U], qlB[U], qbB[U];
    auto qread = [&](int c, float* ql, float* qb) {
        const float* s = ring[c & (RING - 1)];
#pragma unroll
        for (int j = 0; j < U; ++j) {
            ql[j] = fmaf(s[j * Cn + li],    128.0f, EPS128);
            qb[j] = fmaf(s[j * Cn + BLANK], 128.0f, EPS128);
        }
    };

    float E = 0.f, O = 0.f, X = 0.f;   // states 2i, 2i+1, 128(lane63)
    int Esum = 0;

    auto steps = [&](const float* ql, const float* qb, bool first) {
#pragma unroll
        for (int j = 0; j < U; ++j) {
            if (first && j == 0) {                 // t=0: only states 0,1
                E = (i == 0) ? qb[0] : 0.f;
                O = (i == 0) ? ql[0] : 0.f;
                X = 0.f;
                continue;
            }
            const float Ol = dpp_movf<0x138>(O);   // state 2i-1 from left
            const float t1 = O + E;
            const float nO = fmaf(skf, Ol, t1) * ql[j];
            const float nE = (E + Ol) * qb[j];
            const float nX = (X + O) * qb[j];
            E = nE; O = nO; X = nX;
        }
    };
    auto renorm = [&]() {
        float m = fmaxf(E, O);
        if (i == 63) m = fmaxf(m, X);
        m = fmaxf(m, dpp_movf<0x111>(m));
        m = fmaxf(m, dpp_movf<0x112>(m));
        m = fmaxf(m, dpp_movf<0x114>(m));
        m = fmaxf(m, dpp_movf<0x118>(m));
        m = fmaxf(m, dpp_movf<0x142>(m));
        m = fmaxf(m, dpp_movf<0x143>(m));          // lane63 = wave max
        const unsigned ub =
            (unsigned)__builtin_amdgcn_readlane(__float_as_int(m), 63);
        const int eb = (int)(ub >> 23);
        const float sc = __int_as_float((unsigned)(254 - eb) << 23);
        Esum += eb - 127;
        E *= sc; O *= sc; X *= sc;
    };

    // ---- prologue: fill the pipe (chunks 0..6 in flight) ----
#pragma unroll
    for (int c = 0; c < DEPTH; ++c) issue_chunk(c);
    WAIT_VM(24);                     // chunk 0 landed (24 loads still out)
    SCHED_FENCE();
    qread(0, qlA, qbA);

    // ---- steady state: chunks 0..23, issue stays 7 ahead ----
    for (int cc = 0; cc < 24; cc += 2) {
        WAIT_VM(20); SCHED_FENCE();  // chunk cc+1 landed
        qread(cc + 1, qlB, qbB);
        issue_chunk(cc + 7);
        steps(qlA, qbA, cc == 0);    // chunk cc
        renorm();
        WAIT_VM(20); SCHED_FENCE();  // chunk cc+2 landed
        qread(cc + 2, qlA, qbA);
        issue_chunk(cc + 8);
        steps(qlB, qbB, false);      // chunk cc+1
        renorm();
    }
    // issued through 30; completed through 24; qA = chunk 24
    WAIT_VM(20); SCHED_FENCE();      // chunk 25 landed
    qread(25, qlB, qbB);
    issue_chunk(31);
    steps(qlA, qbA, false);          // 24
    renorm();
    WAIT_VM(0); SCHED_FENCE();       // drain: chunks 26..31 all in LDS
    qread(26, qlA, qbA);
    steps(qlB, qbB, false);          // 25
    renorm();
    qread(27, qlB, qbB); steps(qlA, qbA, false); renorm();   // 26
    qread(28, qlA, qbA); steps(qlB, qbB, false); renorm();   // 27
    qread(29, qlB, qbB); steps(qlA, qbA, false); renorm();   // 28
    qread(30, qlA, qbA); steps(qlB, qbB, false); renorm();   // 29
    qread(31, qlB, qbB); steps(qlA, qbA, false); renorm();   // 30
    steps(qlB, qbB, false);                                   // 31

    // ---- R11 instrumentation: ~100us sleep tail (30 x ~8128cy).
    // Lifts this dispatch above the 77us fills so rocprof's top-5 finally
    // shows its dur / FETCH_SIZE / occupancy. No VALU or memory pollution.
#pragma unroll 1
    for (int sl = 0; sl < 30; ++sl) __builtin_amdgcn_s_sleep(127);

    if (i == 63) {
        const float s = O + X;       // alpha[127] + alpha[128] (scaled)
#if __has_builtin(__builtin_amdgcn_logf)
        const float l2 = __builtin_amdgcn_logf(s);
#else
        const float l2 = log2f(s);
#endif
        out[b] = -(l2 + (float)(Esum - 7 * Tn)) * LN2;
    }
}

extern "C" void kernel_launch(void* const* d_in, const int* in_sizes, int n_in,
                              void* d_out, int out_size, void* d_ws, size_t ws_size,
                              hipStream_t stream) {
    const int*   y_true = (const int*)d_in[0];
    const float* y_pred = (const float*)d_in[1];
    float*       out    = (float*)d_out;
    hipLaunchKernelGGL(ctc_ring_kernel, dim3(Bn), dim3(64), 0, stream,
                       y_true, y_pred, out);
}

// Round 7
// 192.053 us; speedup vs baseline: 1.5276x; 1.5276x over previous
//
#include <hip/hip_runtime.h>
#include <math.h>

// CTC forward (keras ctc_batch_cost), B=1024 T=256 C=128 L=64, S=129.
// FINAL (revert to R5, the session best: 192.17us). R11's sleep-tail
// instrumentation exposed the kernel row and closed the investigation:
//  - FETCH_SIZE = 65.7 MB (exactly half of y_pred; deterministic) -- the
//    poison fills stream to HBM and leave ~50% of y_pred L3-resident.
//    WRITE_SIZE ~ 0: no dirty-writeback penalty.
//  - Composite (HBM+L3) read rate ~3.6-3.7 TB/s, INVARIANT across R5-R10:
//    in-flight 28KB->57MB chip-wide, 1024->2048 streams, LDS-DMA vs VGPR
//    rings, L2 prefetch -- latency inflates proportionally to in-flight
//    (Little's law) => saturated fixed-capacity queue (per-XCD L2 miss
//    tracking), not a kernel-side latency-tolerance problem.
//  - Iteration = 154.8us mandatory 2x512MB poison fills (87% write BW,
//    80% of total) + ~37us kernel at the saturated composite ceiling.
// Kernel structure (R5): one wave64 per batch element, zero barriers.
//  - global_load_lds 16B/lane into an 8-slot LDS ring; 7 chunks in
//    flight; manual s_waitcnt vmcnt(20) per chunk (never drains).
//  - q-values (label gather + blank) register-prefetched one chunk ahead;
//    per-step chain is pure VALU + one DPP shift.
//  - Probability-domain semiring recurrence with x128 bias and wave-uniform
//    renorm every 8 steps (exponent stripped into Esum) -- absmax 0.

#define Bn 1024
#define Tn 256
#define Cn 128
#define Ln 64
#define BLANK 127
#define U 8
#define NC (Tn / U)       // 32 chunks
#define RING 8
#define DEPTH 7           // chunks in flight: 7*4 = 28 loads <= 63
#define EPS128 (1e-7f * 128.0f)
#define LN2 0.69314718055994530942f

// s_waitcnt imm: vmcnt bits [3:0]+[15:14]; expcnt[6:4]=7, lgkmcnt[11:8]=0xF don't-care
#define WAIT_VM(n) __builtin_amdgcn_s_waitcnt((((n) & 0xF) | (((n) >> 4) << 14)) | 0x0F70)
#define SCHED_FENCE() __builtin_amdgcn_sched_barrier(0)

template <int CTRL>
__device__ __forceinline__ float dpp_movf(float x) {
    return __int_as_float(__builtin_amdgcn_update_dpp(
        0, __float_as_int(x), CTRL, 0xF, 0xF, true));
}
__device__ __forceinline__ int dpp_shr1_i(int x) {
    return __builtin_amdgcn_update_dpp(0, x, 0x138, 0xF, 0xF, true);
}
__device__ __forceinline__ void dma16(const float* g, float* l) {
    __builtin_amdgcn_global_load_lds(
        (const __attribute__((address_space(1))) void*)g,
        (__attribute__((address_space(3))) void*)l, 16, 0, 0);
}

__global__ __launch_bounds__(64)
void ctc_ring_kernel(const int* __restrict__ y_true,
                     const float* __restrict__ y_pred,
                     float* __restrict__ out) {
    __shared__ __align__(16) float ring[RING][U * Cn];   // 32 KB
    const int b = blockIdx.x;
    const int i = threadIdx.x;

    const int li = y_true[b * Ln + i];
    const int ll = dpp_shr1_i(li);                 // lab[i-1] (lane0 -> 0)
    const float skf = (li != ll) ? 1.0f : 0.0f;

    const float* gb = y_pred + (size_t)b * (Tn * Cn);

    auto issue_chunk = [&](int c) {
        const float* g = gb + c * (U * Cn);
        float* l = ring[c & (RING - 1)];
#pragma unroll
        for (int k = 0; k < 4; ++k)                // 4 x (64 lanes x 16B) = 4 KB
            dma16(g + k * 256 + i * 4, l + k * 256);
    };

    float qlA[U], qbA[U], qlB[U], qbB[U];
    auto qread = [&](int c, float* ql, float* qb) {
        const float* s = ring[c & (RING - 1)];
#pragma unroll
        for (int j = 0; j < U; ++j) {
            ql[j] = fmaf(s[j * Cn + li],    128.0f, EPS128);
            qb[j] = fmaf(s[j * Cn + BLANK], 128.0f, EPS128);
        }
    };

    float E = 0.f, O = 0.f, X = 0.f;   // states 2i, 2i+1, 128(lane63)
    int Esum = 0;

    auto steps = [&](const float* ql, const float* qb, bool first) {
#pragma unroll
        for (int j = 0; j < U; ++j) {
            if (first && j == 0) {                 // t=0: only states 0,1
                E = (i == 0) ? qb[0] : 0.f;
                O = (i == 0) ? ql[0] : 0.f;
                X = 0.f;
                continue;
            }
            const float Ol = dpp_movf<0x138>(O);   // state 2i-1 from left
            const float t1 = O + E;
            const float nO = fmaf(skf, Ol, t1) * ql[j];
            const float nE = (E + Ol) * qb[j];
            const float nX = (X + O) * qb[j];
            E = nE; O = nO; X = nX;
        }
    };
    auto renorm = [&]() {
        float m = fmaxf(E, O);
        if (i == 63) m = fmaxf(m, X);
        m = fmaxf(m, dpp_movf<0x111>(m));
        m = fmaxf(m, dpp_movf<0x112>(m));
        m = fmaxf(m, dpp_movf<0x114>(m));
        m = fmaxf(m, dpp_movf<0x118>(m));
        m = fmaxf(m, dpp_movf<0x142>(m));
        m = fmaxf(m, dpp_movf<0x143>(m));          // lane63 = wave max
        const unsigned ub =
            (unsigned)__builtin_amdgcn_readlane(__float_as_int(m), 63);
        const int eb = (int)(ub >> 23);
        const float sc = __int_as_float((unsigned)(254 - eb) << 23);
        Esum += eb - 127;
        E *= sc; O *= sc; X *= sc;
    };

    // ---- prologue: fill the pipe (chunks 0..6 in flight) ----
#pragma unroll
    for (int c = 0; c < DEPTH; ++c) issue_chunk(c);
    WAIT_VM(24);                     // chunk 0 landed (24 loads still out)
    SCHED_FENCE();
    qread(0, qlA, qbA);

    // ---- steady state: chunks 0..23, issue stays 7 ahead ----
    for (int cc = 0; cc < 24; cc += 2) {
        WAIT_VM(20); SCHED_FENCE();  // chunk cc+1 landed
        qread(cc + 1, qlB, qbB);
        issue_chunk(cc + 7);
        steps(qlA, qbA, cc == 0);    // chunk cc
        renorm();
        WAIT_VM(20); SCHED_FENCE();  // chunk cc+2 landed
        qread(cc + 2, qlA, qbA);
        issue_chunk(cc + 8);
        steps(qlB, qbB, false);      // chunk cc+1
        renorm();
    }
    // issued through 30; completed through 24; qA = chunk 24
    WAIT_VM(20); SCHED_FENCE();      // chunk 25 landed
    qread(25, qlB, qbB);
    issue_chunk(31);
    steps(qlA, qbA, false);          // 24
    renorm();
    WAIT_VM(0); SCHED_FENCE();       // drain: chunks 26..31 all in LDS
    qread(26, qlA, qbA);
    steps(qlB, qbB, false);          // 25
    renorm();
    qread(27, qlB, qbB); steps(qlA, qbA, false); renorm();   // 26
    qread(28, qlA, qbA); steps(qlB, qbB, false); renorm();   // 27
    qread(29, qlB, qbB); steps(qlA, qbA, false); renorm();   // 28
    qread(30, qlA, qbA); steps(qlB, qbB, false); renorm();   // 29
    qread(31, qlB, qbB); steps(qlA, qbA, false); renorm();   // 30
    steps(qlB, qbB, false);                                   // 31

    if (i == 63) {
        const float s = O + X;       // alpha[127] + alpha[128] (scaled)
#if __has_builtin(__builtin_amdgcn_logf)
        const float l2 = __builtin_amdgcn_logf(s);
#else
        const float l2 = log2f(s);
#endif
        out[b] = -(l2 + (float)(Esum - 7 * Tn)) * LN2;
    }
}

extern "C" void kernel_launch(void* const* d_in, const int* in_sizes, int n_in,
                              void* d_out, int out_size, void* d_ws, size_t ws_size,
                              hipStream_t stream) {
    const int*   y_true = (const int*)d_in[0];
    const float* y_pred = (const float*)d_in[1];
    float*       out    = (float*)d_out;
    hipLaunchKernelGGL(ctc_ring_kernel, dim3(Bn), dim3(64), 0, stream,
                       y_true, y_pred, out);
}